// Round 8
// baseline (463.728 us; speedup 1.0000x reference)
//
#include <hip/hip_runtime.h>

// PartialProductAccumulator: 54-step ripple add with dropped carry-out
// == sum of 54 partial products mod 2^108 == binary digits of N = sum cnt_i 2^i.
// FUSED kernel:
//   phase 1: per-bit-column popcount (exact in fp32, max 54), nontemporal
//            streamed from HBM (R5 A/B: removing nt cost +29us), depth-4
//            register pipeline, 1 float4 column (= one nibble position) / thread.
//   phase 2: radix-16 reformulation -- thread's 4 counts collapse to one
//            digit v = c0+2c1+4c2+8c3 (<=810, exact); row value = sum v_j 16^j,
//            so carry propagation is a 27-step radix-16 chain in REGISTERS
//            (t=v+c; digit=t&15; c=t>>4; carry out of digit 26 dropped
//            == mod 2^108). No 108-step dependent LDS chain.
// Block = 432 threads = 16 rows x 27 nibbles; 1024 blocks = 4 blocks/CU.

#define N_PP   54
#define BITS   108
#define BATCH  16384
#define ROW_F4 (BITS / 4)                    // 27 float4 (nibbles) per row
#define PLANE_F4 ((size_t)BATCH * ROW_F4)    // 442368 float4 per p-plane
#define ROWS_PB 16                           // batch rows per block
#define TPB     (ROWS_PB * ROW_F4)           // 432 threads

typedef float vf4 __attribute__((ext_vector_type(4)));

__global__ __launch_bounds__(TPB)
void ppacc_fused(const vf4* __restrict__ pps, vf4* __restrict__ out) {
    __shared__ int nib[ROWS_PB][ROW_F4 + 1];  // stride 28: worst ~2-way (free)

    const int tid = threadIdx.x;
    const size_t i0 = (size_t)blockIdx.x * TPB + tid;
    const vf4* p = pps + i0;

    // ---- phase 1: column popcount, depth-4 nt pipeline ----
    vf4 acc = (vf4)(0.f);

    vf4 v0 = __builtin_nontemporal_load(p + 0 * PLANE_F4);
    vf4 v1 = __builtin_nontemporal_load(p + 1 * PLANE_F4);
    vf4 v2 = __builtin_nontemporal_load(p + 2 * PLANE_F4);
    vf4 v3 = __builtin_nontemporal_load(p + 3 * PLANE_F4);

    for (int q = 4; q + 4 <= N_PP - 2; q += 4) {      // planes 4..51
        const vf4* pq = p + (size_t)q * PLANE_F4;
        vf4 n0 = __builtin_nontemporal_load(pq + 0 * PLANE_F4);
        vf4 n1 = __builtin_nontemporal_load(pq + 1 * PLANE_F4);
        vf4 n2 = __builtin_nontemporal_load(pq + 2 * PLANE_F4);
        vf4 n3 = __builtin_nontemporal_load(pq + 3 * PLANE_F4);
        acc += v0; acc += v1; acc += v2; acc += v3;
        v0 = n0; v1 = n1; v2 = n2; v3 = n3;
    }
    vf4 e0 = __builtin_nontemporal_load(p + (size_t)(N_PP - 2) * PLANE_F4);
    vf4 e1 = __builtin_nontemporal_load(p + (size_t)(N_PP - 1) * PLANE_F4);
    acc += v0; acc += v1; acc += v2; acc += v3;
    acc += e0; acc += e1;

    // ---- phase 2: radix-16 carry propagation ----
    const int row = tid / ROW_F4;
    const int j   = tid % ROW_F4;

    // local digit at weight 16^j; counts <=54 so v <= 810, exact in fp32
    nib[row][j] = (int)(acc.x + 2.0f * acc.y + 4.0f * acc.z + 8.0f * acc.w);
    __syncthreads();

    if (tid < ROWS_PB) {
        int r[ROW_F4];
#pragma unroll
        for (int k = 0; k < ROW_F4; ++k) r[k] = nib[tid][k];   // independent reads
        int c = 0;
#pragma unroll
        for (int k = 0; k < ROW_F4; ++k) {                     // 27-step reg chain
            const int t = r[k] + c;
            r[k] = t & 15;
            c = t >> 4;                // carry out of digit 26 dropped (mod 2^108)
        }
#pragma unroll
        for (int k = 0; k < ROW_F4; ++k) nib[tid][k] = r[k];
    }
    __syncthreads();

    // expand own nibble to 4 float bits, nontemporal store (no reuse)
    const int m = nib[row][j];
    vf4 o;
    o.x = (float)(m & 1);
    o.y = (float)((m >> 1) & 1);
    o.z = (float)((m >> 2) & 1);
    o.w = (float)((m >> 3) & 1);
    __builtin_nontemporal_store(o, out + i0);
}

extern "C" void kernel_launch(void* const* d_in, const int* in_sizes, int n_in,
                              void* d_out, int out_size, void* d_ws, size_t ws_size,
                              hipStream_t stream) {
    const vf4* pps = (const vf4*)d_in[0];
    vf4* out = (vf4*)d_out;
    ppacc_fused<<<(int)(PLANE_F4 / TPB), TPB, 0, stream>>>(pps, out);   // 1024 blocks
}